// Round 1
// baseline (16608.226 us; speedup 1.0000x reference)
//
#include <hip/hip_runtime.h>

#define N_NODES 100000
#define N_EDGES 1600000
#define N_GRAPHS 64
#define IN_F 128
#define HID 256
#define OUT_F 10

// ---------------- degree / norm ----------------
__global__ void k_init_deg(float* deg) {
    int i = blockIdx.x * blockDim.x + threadIdx.x;
    if (i < N_NODES) deg[i] = 1.0f;   // self loop
}

__global__ void k_deg(const int* __restrict__ dst, float* __restrict__ deg) {
    int e = blockIdx.x * blockDim.x + threadIdx.x;
    if (e < N_EDGES) atomicAdd(&deg[dst[e]], 1.0f);
}

__global__ void k_dinv(float* deg) {
    int i = blockIdx.x * blockDim.x + threadIdx.x;
    if (i < N_NODES) deg[i] = rsqrtf(deg[i]);   // deg >= 1 always
}

// ---------------- aggregation: agg = A_hat @ h (width W) ----------------
// self-loop init: agg[i] = dinv[i]^2 * h[i]
template<int W>
__global__ void k_self(const float* __restrict__ h, const float* __restrict__ dinv,
                       float* __restrict__ agg) {
    int t = blockIdx.x * blockDim.x + threadIdx.x;   // over N*(W/4)
    int i = t / (W / 4);
    int c = t % (W / 4);
    if (i >= N_NODES) return;
    float w = dinv[i] * dinv[i];
    float4 v = ((const float4*)(h + (size_t)i * W))[c];
    v.x *= w; v.y *= w; v.z *= w; v.w *= w;
    ((float4*)(agg + (size_t)i * W))[c] = v;
}

template<int W>
__global__ void k_scatter(const float* __restrict__ h, const int* __restrict__ src,
                          const int* __restrict__ dst, const float* __restrict__ dinv,
                          float* __restrict__ agg) {
    int t = blockIdx.x * blockDim.x + threadIdx.x;   // over E*(W/4)
    int e = t / (W / 4);
    int c = t % (W / 4);
    if (e >= N_EDGES) return;
    int s = src[e], d = dst[e];
    float w = dinv[s] * dinv[d];
    float4 v = ((const float4*)(h + (size_t)s * W))[c];
    float* o = agg + (size_t)d * W + c * 4;
    atomicAdd(o + 0, v.x * w);
    atomicAdd(o + 1, v.y * w);
    atomicAdd(o + 2, v.z * w);
    atomicAdd(o + 3, v.w * w);
}

// ---------------- GEMM: C = relu(A @ W^T + bias), A:[M,K], W:[256,K] ----------------
// FUSE: instead of storing C, atomicAdd into pooled[batch[row]*HID + col]
template<int K, bool FUSE>
__global__ __launch_bounds__(256)
void k_gemm(const float* __restrict__ A, const float* __restrict__ Wm,
            const float* __restrict__ bias, float* __restrict__ C,
            const int* __restrict__ batch, float* __restrict__ pooled) {
    __shared__ float As[64][132];
    __shared__ float Ws[64][132];
    int row0 = blockIdx.x * 64;
    int col0 = blockIdx.y * 64;
    int tid = threadIdx.x;
    int tr = tid % 16, tc = tid / 16;
    float acc[4][4] = {};
    for (int kc = 0; kc < K; kc += 128) {
        #pragma unroll
        for (int l = 0; l < 8; ++l) {
            int idx = l * 256 + tid;       // 0..2047
            int r = idx >> 5;              // 0..63
            int c4 = idx & 31;             // 0..31 (float4 within 128-chunk)
            int grow = row0 + r;
            float4 v = make_float4(0.f, 0.f, 0.f, 0.f);
            if (grow < N_NODES) v = ((const float4*)(A + (size_t)grow * K + kc))[c4];
            *((float4*)&As[r][c4 * 4]) = v;
            float4 wv = ((const float4*)(Wm + (size_t)(col0 + r) * K + kc))[c4];
            *((float4*)&Ws[r][c4 * 4]) = wv;
        }
        __syncthreads();
        #pragma unroll
        for (int k = 0; k < 128; k += 4) {
            float4 a[4], b[4];
            #pragma unroll
            for (int r = 0; r < 4; ++r) a[r] = *((float4*)&As[tr * 4 + r][k]);
            #pragma unroll
            for (int c = 0; c < 4; ++c) b[c] = *((float4*)&Ws[tc * 4 + c][k]);
            #pragma unroll
            for (int r = 0; r < 4; ++r)
                #pragma unroll
                for (int c = 0; c < 4; ++c)
                    acc[r][c] += a[r].x * b[c].x + a[r].y * b[c].y
                               + a[r].z * b[c].z + a[r].w * b[c].w;
        }
        __syncthreads();
    }
    #pragma unroll
    for (int r = 0; r < 4; ++r) {
        int grow = row0 + tr * 4 + r;
        if (grow >= N_NODES) continue;
        int g = 0;
        if (FUSE) g = batch[grow];
        #pragma unroll
        for (int c = 0; c < 4; ++c) {
            int gcol = col0 + tc * 4 + c;
            float v = acc[r][c] + bias[gcol];
            v = fmaxf(v, 0.0f);
            if (FUSE) atomicAdd(&pooled[g * HID + gcol], v);
            else C[(size_t)grow * HID + gcol] = v;
        }
    }
}

// ---------------- pooling counts + final FC ----------------
__global__ void k_cnt(const int* __restrict__ batch, float* __restrict__ cnt) {
    int i = blockIdx.x * blockDim.x + threadIdx.x;
    if (i < N_NODES) atomicAdd(&cnt[batch[i]], 1.0f);
}

__global__ void k_final(const float* __restrict__ pooled, const float* __restrict__ cnt,
                        const float* __restrict__ Wfc, const float* __restrict__ bfc,
                        float* __restrict__ out) {
    int t = blockIdx.x * blockDim.x + threadIdx.x;
    if (t >= N_GRAPHS * OUT_F) return;
    int g = t / OUT_F, o = t % OUT_F;
    float inv = 1.0f / fmaxf(cnt[g], 1.0f);
    float s = 0.f;
    for (int k = 0; k < HID; ++k) s += pooled[g * HID + k] * Wfc[o * HID + k];
    out[t] = s * inv + bfc[o];
}

extern "C" void kernel_launch(void* const* d_in, const int* in_sizes, int n_in,
                              void* d_out, int out_size, void* d_ws, size_t ws_size,
                              hipStream_t stream) {
    const float* x    = (const float*)d_in[0];
    const int*   ei   = (const int*)d_in[1];      // src = ei, dst = ei + E
    const int*   bat  = (const int*)d_in[2];
    const float* W1   = (const float*)d_in[3];
    const float* b1   = (const float*)d_in[4];
    const float* W2   = (const float*)d_in[5];
    const float* b2   = (const float*)d_in[6];
    const float* Wfc  = (const float*)d_in[7];
    const float* bfc  = (const float*)d_in[8];
    float* out = (float*)d_out;

    const int* src = ei;
    const int* dst = ei + N_EDGES;

    float* ws = (float*)d_ws;
    size_t o_dinv   = 0;
    size_t o_pooled = 100096;                          // N rounded up
    size_t o_cnt    = o_pooled + (size_t)N_GRAPHS * HID;   // contiguous after pooled
    size_t o_h1     = o_cnt + 128;
    size_t o_aggB   = o_h1 + (size_t)N_NODES * HID;
    float* dinv   = ws + o_dinv;
    float* pooled = ws + o_pooled;
    float* cnt    = ws + o_cnt;
    float* h1     = ws + o_h1;
    float* aggB   = ws + o_aggB;   // used as aggx [N,128] then aggh [N,256]

    const int B = 256;

    // norm
    k_init_deg<<<(N_NODES + B - 1) / B, B, 0, stream>>>(dinv);
    k_deg<<<(N_EDGES + B - 1) / B, B, 0, stream>>>(dst, dinv);
    k_dinv<<<(N_NODES + B - 1) / B, B, 0, stream>>>(dinv);

    // zero pooled + cnt (contiguous)
    hipMemsetAsync(pooled, 0, ((size_t)N_GRAPHS * HID + 128) * sizeof(float), stream);
    k_cnt<<<(N_NODES + B - 1) / B, B, 0, stream>>>(bat, cnt);

    // layer 1: aggregate x (width 128), then GEMM+relu -> h1
    {
        size_t t1 = (size_t)N_NODES * (IN_F / 4);
        k_self<IN_F><<<(t1 + B - 1) / B, B, 0, stream>>>(x, dinv, aggB);
        size_t t2 = (size_t)N_EDGES * (IN_F / 4);
        k_scatter<IN_F><<<(t2 + B - 1) / B, B, 0, stream>>>(x, src, dst, dinv, aggB);
        dim3 grid((N_NODES + 63) / 64, HID / 64);
        k_gemm<IN_F, false><<<grid, 256, 0, stream>>>(aggB, W1, b1, h1, nullptr, nullptr);
    }

    // layer 2: aggregate h1 (width 256), then GEMM+relu fused with pooling
    {
        size_t t1 = (size_t)N_NODES * (HID / 4);
        k_self<HID><<<(t1 + B - 1) / B, B, 0, stream>>>(h1, dinv, aggB);
        size_t t2 = (size_t)N_EDGES * (HID / 4);
        k_scatter<HID><<<(t2 + B - 1) / B, B, 0, stream>>>(h1, src, dst, dinv, aggB);
        dim3 grid((N_NODES + 63) / 64, HID / 64);
        k_gemm<HID, true><<<grid, 256, 0, stream>>>(aggB, W2, b2, nullptr, bat, pooled);
    }

    // final FC
    k_final<<<(N_GRAPHS * OUT_F + B - 1) / B, B, 0, stream>>>(pooled, cnt, Wfc, bfc, out);
}

// Round 2
// 3118.923 us; speedup vs baseline: 5.3250x; 5.3250x over previous
//
#include <hip/hip_runtime.h>

#define N_NODES 100000
#define N_EDGES 1600000
#define N_GRAPHS 64
#define IN_F 128
#define HID 256
#define OUT_F 10

// ---------------- CSR build ----------------
__global__ void k_count(const int* __restrict__ dst, int* __restrict__ cnt) {
    int e = blockIdx.x * blockDim.x + threadIdx.x;
    if (e < N_EDGES) atomicAdd(&cnt[dst[e]], 1);
}

__global__ void k_dinv(const int* __restrict__ cnt, float* __restrict__ dinv) {
    int i = blockIdx.x * blockDim.x + threadIdx.x;
    if (i < N_NODES) dinv[i] = rsqrtf((float)cnt[i] + 1.0f);  // +1 self loop
}

// single-block exclusive scan (Hillis-Steele over 1024 chunks with carry)
__global__ void k_scan(const int* __restrict__ cnt, int* __restrict__ rowptr) {
    __shared__ int sm[1024];
    __shared__ int carry;
    int t = threadIdx.x;
    if (t == 0) carry = 0;
    __syncthreads();
    for (int base = 0; base < N_NODES; base += 1024) {
        int v = (base + t < N_NODES) ? cnt[base + t] : 0;
        int x = v;
        sm[t] = x;
        __syncthreads();
        for (int off = 1; off < 1024; off <<= 1) {
            int add = (t >= off) ? sm[t - off] : 0;
            __syncthreads();
            x += add;
            sm[t] = x;
            __syncthreads();
        }
        if (base + t < N_NODES) rowptr[base + t] = carry + x - v;  // exclusive
        __syncthreads();
        if (t == 0) carry += sm[1023];
        __syncthreads();
    }
}

__global__ void k_fill(const int* __restrict__ src, const int* __restrict__ dst,
                       const int* __restrict__ rowptr, int* __restrict__ fill,
                       int* __restrict__ col) {
    int e = blockIdx.x * blockDim.x + threadIdx.x;
    if (e >= N_EDGES) return;
    int d = dst[e];
    int p = rowptr[d] + atomicAdd(&fill[d], 1);
    col[p] = src[e];
}

// ---------------- aggregation: out[i] = dinv[i]^2*h[i] + sum_j dinv[i]*dinv[j]*h[j] ----------------
// one wave per node; lane covers W/64 contiguous floats
template<int W>
__global__ void __launch_bounds__(256)
k_agg(const float* __restrict__ h, const float* __restrict__ dinv,
      const int* __restrict__ rowptr, const int* __restrict__ cnt,
      const int* __restrict__ col, float* __restrict__ out) {
    int wid = threadIdx.x >> 6, lane = threadIdx.x & 63;
    int i = blockIdx.x * 4 + wid;
    if (i >= N_NODES) return;
    float dd = dinv[i];
    int beg = rowptr[i], num = cnt[i];
    constexpr int V = W / 64;   // 2 or 4
    float acc[V];
    {
        const float* p = h + (size_t)i * W + lane * V;
        float s = dd * dd;
        if constexpr (V == 4) { float4 v = *(const float4*)p; acc[0]=s*v.x; acc[1]=s*v.y; acc[2]=s*v.z; acc[3]=s*v.w; }
        else                  { float2 v = *(const float2*)p; acc[0]=s*v.x; acc[1]=s*v.y; }
    }
    for (int k = 0; k < num; ++k) {
        int s = col[beg + k];
        float w = dd * dinv[s];
        const float* p = h + (size_t)s * W + lane * V;
        if constexpr (V == 4) { float4 v = *(const float4*)p; acc[0]+=w*v.x; acc[1]+=w*v.y; acc[2]+=w*v.z; acc[3]+=w*v.w; }
        else                  { float2 v = *(const float2*)p; acc[0]+=w*v.x; acc[1]+=w*v.y; }
    }
    float* o = out + (size_t)i * W + lane * V;
    if constexpr (V == 4) *(float4*)o = make_float4(acc[0], acc[1], acc[2], acc[3]);
    else                  *(float2*)o = make_float2(acc[0], acc[1]);
}

// ---------------- GEMM: C = relu(A @ W^T + bias), A:[M,K], W:[256,K] ----------------
// BM=128, BN=128, BK=32, 256 threads, 8x8 micro tile, transposed LDS
template<int K, bool FUSE>
__global__ void __launch_bounds__(256)
k_gemm(const float* __restrict__ A, const float* __restrict__ Wm,
       const float* __restrict__ bias, float* __restrict__ C,
       const int* __restrict__ batch, float* __restrict__ pooled) {
    __shared__ float As[32][132];   // [k][m]
    __shared__ float Bs[32][132];   // [k][n]
    int row0 = blockIdx.x * 128;
    int col0 = blockIdx.y * 128;
    int t = threadIdx.x;
    int tm = t >> 4;   // 0..15 -> m = tm*8
    int tn = t & 15;   // 0..15 -> n = tn*8
    float acc[8][8] = {};
    for (int kc = 0; kc < K; kc += 32) {
        #pragma unroll
        for (int i = 0; i < 4; ++i) {
            int idx = i * 256 + t;            // 0..1023
            int r = idx >> 3;                 // 0..127
            int kq = idx & 7;                 // float4 within 32-k chunk
            int grow = row0 + r;
            float4 v = make_float4(0.f, 0.f, 0.f, 0.f);
            if (grow < N_NODES) v = *(const float4*)(A + (size_t)grow * K + kc + kq * 4);
            As[kq*4+0][r] = v.x; As[kq*4+1][r] = v.y; As[kq*4+2][r] = v.z; As[kq*4+3][r] = v.w;
        }
        #pragma unroll
        for (int i = 0; i < 4; ++i) {
            int idx = i * 256 + t;
            int r = idx >> 3;                 // 0..127 (n)
            int kq = idx & 7;
            float4 v = *(const float4*)(Wm + (size_t)(col0 + r) * K + kc + kq * 4);
            Bs[kq*4+0][r] = v.x; Bs[kq*4+1][r] = v.y; Bs[kq*4+2][r] = v.z; Bs[kq*4+3][r] = v.w;
        }
        __syncthreads();
        #pragma unroll 4
        for (int k = 0; k < 32; ++k) {
            float a[8], b[8];
            *(float4*)&a[0] = *(float4*)&As[k][tm * 8];
            *(float4*)&a[4] = *(float4*)&As[k][tm * 8 + 4];
            *(float4*)&b[0] = *(float4*)&Bs[k][tn * 8];
            *(float4*)&b[4] = *(float4*)&Bs[k][tn * 8 + 4];
            #pragma unroll
            for (int m = 0; m < 8; ++m)
                #pragma unroll
                for (int n = 0; n < 8; ++n)
                    acc[m][n] += a[m] * b[n];
        }
        __syncthreads();
    }
    // epilogue
    float bv[8];
    #pragma unroll
    for (int n = 0; n < 8; ++n) bv[n] = bias[col0 + tn * 8 + n];
    #pragma unroll
    for (int m = 0; m < 8; ++m) {
        int grow = row0 + tm * 8 + m;
        if (grow >= N_NODES) continue;
        if (FUSE) {
            int g = batch[grow];
            #pragma unroll
            for (int n = 0; n < 8; ++n) {
                float v = fmaxf(acc[m][n] + bv[n], 0.f);
                atomicAdd(&pooled[g * HID + col0 + tn * 8 + n], v);
            }
        } else {
            float4 v0, v1;
            v0.x = fmaxf(acc[m][0] + bv[0], 0.f);
            v0.y = fmaxf(acc[m][1] + bv[1], 0.f);
            v0.z = fmaxf(acc[m][2] + bv[2], 0.f);
            v0.w = fmaxf(acc[m][3] + bv[3], 0.f);
            v1.x = fmaxf(acc[m][4] + bv[4], 0.f);
            v1.y = fmaxf(acc[m][5] + bv[5], 0.f);
            v1.z = fmaxf(acc[m][6] + bv[6], 0.f);
            v1.w = fmaxf(acc[m][7] + bv[7], 0.f);
            float* o = C + (size_t)grow * HID + col0 + tn * 8;
            *(float4*)o = v0;
            *(float4*)(o + 4) = v1;
        }
    }
}

// ---------------- pooling counts + final FC ----------------
__global__ void k_cnt(const int* __restrict__ batch, float* __restrict__ cntg) {
    int i = blockIdx.x * blockDim.x + threadIdx.x;
    if (i < N_NODES) atomicAdd(&cntg[batch[i]], 1.0f);
}

__global__ void k_final(const float* __restrict__ pooled, const float* __restrict__ cntg,
                        const float* __restrict__ Wfc, const float* __restrict__ bfc,
                        float* __restrict__ out) {
    int t = blockIdx.x * blockDim.x + threadIdx.x;
    if (t >= N_GRAPHS * OUT_F) return;
    int g = t / OUT_F, o = t % OUT_F;
    float inv = 1.0f / fmaxf(cntg[g], 1.0f);
    float s = 0.f;
    for (int k = 0; k < HID; ++k) s += pooled[g * HID + k] * Wfc[o * HID + k];
    out[t] = s * inv + bfc[o];
}

extern "C" void kernel_launch(void* const* d_in, const int* in_sizes, int n_in,
                              void* d_out, int out_size, void* d_ws, size_t ws_size,
                              hipStream_t stream) {
    const float* x    = (const float*)d_in[0];
    const int*   ei   = (const int*)d_in[1];
    const int*   bat  = (const int*)d_in[2];
    const float* W1   = (const float*)d_in[3];
    const float* b1   = (const float*)d_in[4];
    const float* W2   = (const float*)d_in[5];
    const float* b2   = (const float*)d_in[6];
    const float* Wfc  = (const float*)d_in[7];
    const float* bfc  = (const float*)d_in[8];
    float* out = (float*)d_out;

    const int* src = ei;
    const int* dst = ei + N_EDGES;

    float* ws = (float*)d_ws;
    // layout (4B units)
    float* dinv    = ws + 0;                 // 100096
    float* pooled  = ws + 100096;            // 16384
    float* cntg    = ws + 116480;            // 128
    int*   cnt     = (int*)(ws + 116608);    // 100096
    int*   rowptr  = (int*)(ws + 216704);    // 100224
    int*   fill    = (int*)(ws + 316928);    // 100096
    int*   col     = (int*)(ws + 417024);    // 1600000
    float* h1      = ws + 2017024;           // 25600000
    float* agg     = ws + 27617024;          // 25600000

    const int B = 256;

    // zero: pooled+cntg, cnt..fill (covers rowptr harmlessly)
    hipMemsetAsync(pooled, 0, (16384 + 128) * 4, stream);
    hipMemsetAsync(cnt, 0, (size_t)(417024 - 116608) * 4, stream);

    k_count<<<(N_EDGES + B - 1) / B, B, 0, stream>>>(dst, cnt);
    k_dinv<<<(N_NODES + B - 1) / B, B, 0, stream>>>(cnt, dinv);
    k_scan<<<1, 1024, 0, stream>>>(cnt, rowptr);
    k_fill<<<(N_EDGES + B - 1) / B, B, 0, stream>>>(src, dst, rowptr, fill, col);
    k_cnt<<<(N_NODES + B - 1) / B, B, 0, stream>>>(bat, cntg);

    // layer 1: agg = A_hat @ x (width 128), h1 = relu(agg @ W1^T + b1)
    k_agg<IN_F><<<(N_NODES + 3) / 4, 256, 0, stream>>>(x, dinv, rowptr, cnt, col, agg);
    {
        dim3 grid((N_NODES + 127) / 128, HID / 128);
        k_gemm<IN_F, false><<<grid, 256, 0, stream>>>(agg, W1, b1, h1, nullptr, nullptr);
    }

    // layer 2: agg = A_hat @ h1 (width 256), pooled += relu(agg @ W2^T + b2)
    k_agg<HID><<<(N_NODES + 3) / 4, 256, 0, stream>>>(h1, dinv, rowptr, cnt, col, agg);
    {
        dim3 grid((N_NODES + 127) / 128, HID / 128);
        k_gemm<HID, true><<<grid, 256, 0, stream>>>(agg, W2, b2, nullptr, bat, pooled);
    }

    k_final<<<(N_GRAPHS * OUT_F + B - 1) / B, B, 0, stream>>>(pooled, cntg, Wfc, bfc, out);
}

// Round 3
// 1623.372 us; speedup vs baseline: 10.2307x; 1.9213x over previous
//
#include <hip/hip_runtime.h>

#define N_NODES 100000
#define N_EDGES 1600000
#define N_GRAPHS 64
#define IN_F 128
#define HID 256
#define OUT_F 10

// ---------------- CSR build ----------------
__global__ void k_count(const int* __restrict__ dst, int* __restrict__ cnt) {
    int e = blockIdx.x * blockDim.x + threadIdx.x;
    if (e < N_EDGES) atomicAdd(&cnt[dst[e]], 1);
}

__global__ void k_dinv(const int* __restrict__ cnt, float* __restrict__ dinv) {
    int i = blockIdx.x * blockDim.x + threadIdx.x;
    if (i < N_NODES) dinv[i] = rsqrtf((float)cnt[i] + 1.0f);  // +1 self loop
}

// single-block exclusive scan (Hillis-Steele over 1024 chunks with carry)
__global__ void k_scan(const int* __restrict__ cnt, int* __restrict__ rowptr) {
    __shared__ int sm[1024];
    __shared__ int carry;
    int t = threadIdx.x;
    if (t == 0) carry = 0;
    __syncthreads();
    for (int base = 0; base < N_NODES; base += 1024) {
        int v = (base + t < N_NODES) ? cnt[base + t] : 0;
        int x = v;
        sm[t] = x;
        __syncthreads();
        for (int off = 1; off < 1024; off <<= 1) {
            int add = (t >= off) ? sm[t - off] : 0;
            __syncthreads();
            x += add;
            sm[t] = x;
            __syncthreads();
        }
        if (base + t < N_NODES) rowptr[base + t] = carry + x - v;  // exclusive
        __syncthreads();
        if (t == 0) carry += sm[1023];
        __syncthreads();
    }
}

__global__ void k_fill(const int* __restrict__ src, const int* __restrict__ dst,
                       const int* __restrict__ rowptr, int* __restrict__ fill,
                       int* __restrict__ col) {
    int e = blockIdx.x * blockDim.x + threadIdx.x;
    if (e >= N_EDGES) return;
    int d = dst[e];
    int p = rowptr[d] + atomicAdd(&fill[d], 1);
    col[p] = src[e];
}

// ---------------- aggregation ----------------
template<int W>
__global__ void __launch_bounds__(256)
k_agg(const float* __restrict__ h, const float* __restrict__ dinv,
      const int* __restrict__ rowptr, const int* __restrict__ cnt,
      const int* __restrict__ col, float* __restrict__ out) {
    int wid = threadIdx.x >> 6, lane = threadIdx.x & 63;
    int i = blockIdx.x * 4 + wid;
    if (i >= N_NODES) return;
    float dd = dinv[i];
    int beg = rowptr[i], num = cnt[i];
    constexpr int V = W / 64;   // 2 or 4
    float acc[V];
    {
        const float* p = h + (size_t)i * W + lane * V;
        float s = dd * dd;
        if constexpr (V == 4) { float4 v = *(const float4*)p; acc[0]=s*v.x; acc[1]=s*v.y; acc[2]=s*v.z; acc[3]=s*v.w; }
        else                  { float2 v = *(const float2*)p; acc[0]=s*v.x; acc[1]=s*v.y; }
    }
    for (int k = 0; k < num; ++k) {
        int s = col[beg + k];
        float w = dd * dinv[s];
        const float* p = h + (size_t)s * W + lane * V;
        if constexpr (V == 4) { float4 v = *(const float4*)p; acc[0]+=w*v.x; acc[1]+=w*v.y; acc[2]+=w*v.z; acc[3]+=w*v.w; }
        else                  { float2 v = *(const float2*)p; acc[0]+=w*v.x; acc[1]+=w*v.y; }
    }
    float* o = out + (size_t)i * W + lane * V;
    if constexpr (V == 4) *(float4*)o = make_float4(acc[0], acc[1], acc[2], acc[3]);
    else                  *(float2*)o = make_float2(acc[0], acc[1]);
}

// ---------------- GEMM: C = relu(A @ W^T + bias), A:[M,K], W:[256,K] ----------------
// BM=128, BN=128, BK=32, 256 threads, 8x8 micro tile (split-64 cols), transposed LDS
template<int K, bool FUSE>
__global__ void __launch_bounds__(256)
k_gemm(const float* __restrict__ A, const float* __restrict__ Wm,
       const float* __restrict__ bias, float* __restrict__ C,
       const int* __restrict__ batch, float* __restrict__ pooled) {
    __shared__ float smem[2 * 32 * 132];
    float (*As)[132] = (float(*)[132])smem;            // [k][m]
    float (*Bs)[132] = (float(*)[132])(smem + 32*132); // [k][n]
    int row0 = blockIdx.x * 128;
    int col0 = blockIdx.y * 128;
    int t = threadIdx.x;
    int tm = t >> 4;   // 0..15 -> rows tm*8 .. tm*8+7
    int tn = t & 15;   // 0..15 -> cols tn*4..+3 and 64+tn*4..+3
    float acc[8][8] = {};
    for (int kc = 0; kc < K; kc += 32) {
        #pragma unroll
        for (int i = 0; i < 4; ++i) {
            int idx = i * 256 + t;            // 0..1023
            int r = idx >> 3;                 // 0..127
            int kq = idx & 7;                 // float4 within 32-k chunk
            int grow = row0 + r;
            float4 v = make_float4(0.f, 0.f, 0.f, 0.f);
            if (grow < N_NODES) v = *(const float4*)(A + (size_t)grow * K + kc + kq * 4);
            As[kq*4+0][r] = v.x; As[kq*4+1][r] = v.y; As[kq*4+2][r] = v.z; As[kq*4+3][r] = v.w;
        }
        #pragma unroll
        for (int i = 0; i < 4; ++i) {
            int idx = i * 256 + t;
            int r = idx >> 3;                 // 0..127 (n)
            int kq = idx & 7;
            float4 v = *(const float4*)(Wm + (size_t)(col0 + r) * K + kc + kq * 4);
            Bs[kq*4+0][r] = v.x; Bs[kq*4+1][r] = v.y; Bs[kq*4+2][r] = v.z; Bs[kq*4+3][r] = v.w;
        }
        __syncthreads();
        #pragma unroll 4
        for (int k = 0; k < 32; ++k) {
            float a[8], b[8];
            *(float4*)&a[0] = *(float4*)&As[k][tm * 8];
            *(float4*)&a[4] = *(float4*)&As[k][tm * 8 + 4];
            *(float4*)&b[0] = *(float4*)&Bs[k][tn * 4];        // banks 4tn..: 2-way, free
            *(float4*)&b[4] = *(float4*)&Bs[k][tn * 4 + 64];
            #pragma unroll
            for (int m = 0; m < 8; ++m)
                #pragma unroll
                for (int n = 0; n < 8; ++n)
                    acc[m][n] += a[m] * b[n];
        }
        __syncthreads();
    }
    // bias + relu into acc
    float bv[8];
    #pragma unroll
    for (int n = 0; n < 4; ++n) {
        bv[n]     = bias[col0 + tn * 4 + n];
        bv[4 + n] = bias[col0 + 64 + tn * 4 + n];
    }
    #pragma unroll
    for (int m = 0; m < 8; ++m)
        #pragma unroll
        for (int n = 0; n < 8; ++n)
            acc[m][n] = fmaxf(acc[m][n] + bv[n], 0.f);

    if (!FUSE) {
        #pragma unroll
        for (int m = 0; m < 8; ++m) {
            int grow = row0 + tm * 8 + m;
            if (grow >= N_NODES) continue;
            float* o = C + (size_t)grow * HID + col0;
            *(float4*)(o + tn * 4)      = make_float4(acc[m][0], acc[m][1], acc[m][2], acc[m][3]);
            *(float4*)(o + 64 + tn * 4) = make_float4(acc[m][4], acc[m][5], acc[m][6], acc[m][7]);
        }
    } else {
        // per-block segment reduction: batch is sorted -> few graphs per 128-row tile
        float* red = smem;   // [16][128], reuse (all LDS reads done at loop-end barrier)
        int rhi = row0 + 127; if (rhi >= N_NODES) rhi = N_NODES - 1;
        int glo = batch[row0], ghi = batch[rhi];
        int gm[8];
        #pragma unroll
        for (int m = 0; m < 8; ++m) {
            int grow = row0 + tm * 8 + m;
            gm[m] = (grow < N_NODES) ? batch[grow] : -1;
        }
        for (int g = glo; g <= ghi; ++g) {
            float p[8] = {};
            #pragma unroll
            for (int m = 0; m < 8; ++m)
                if (gm[m] == g) {
                    #pragma unroll
                    for (int n = 0; n < 8; ++n) p[n] += acc[m][n];
                }
            #pragma unroll
            for (int n = 0; n < 4; ++n) {
                red[tm * 128 + tn * 4 + n]      = p[n];
                red[tm * 128 + 64 + tn * 4 + n] = p[4 + n];
            }
            __syncthreads();
            if (t < 128) {
                float s = 0.f;
                #pragma unroll
                for (int r = 0; r < 16; ++r) s += red[r * 128 + t];
                if (s != 0.f) atomicAdd(&pooled[g * HID + col0 + t], s);
            }
            __syncthreads();
        }
    }
}

// ---------------- pooling counts + final FC ----------------
__global__ void k_cnt(const int* __restrict__ batch, float* __restrict__ cntg) {
    int i = blockIdx.x * blockDim.x + threadIdx.x;
    if (i < N_NODES) atomicAdd(&cntg[batch[i]], 1.0f);
}

__global__ void k_final(const float* __restrict__ pooled, const float* __restrict__ cntg,
                        const float* __restrict__ Wfc, const float* __restrict__ bfc,
                        float* __restrict__ out) {
    int t = blockIdx.x * blockDim.x + threadIdx.x;
    if (t >= N_GRAPHS * OUT_F) return;
    int g = t / OUT_F, o = t % OUT_F;
    float inv = 1.0f / fmaxf(cntg[g], 1.0f);
    float s = 0.f;
    for (int k = 0; k < HID; ++k) s += pooled[g * HID + k] * Wfc[o * HID + k];
    out[t] = s * inv + bfc[o];
}

extern "C" void kernel_launch(void* const* d_in, const int* in_sizes, int n_in,
                              void* d_out, int out_size, void* d_ws, size_t ws_size,
                              hipStream_t stream) {
    const float* x    = (const float*)d_in[0];
    const int*   ei   = (const int*)d_in[1];
    const int*   bat  = (const int*)d_in[2];
    const float* W1   = (const float*)d_in[3];
    const float* b1   = (const float*)d_in[4];
    const float* W2   = (const float*)d_in[5];
    const float* b2   = (const float*)d_in[6];
    const float* Wfc  = (const float*)d_in[7];
    const float* bfc  = (const float*)d_in[8];
    float* out = (float*)d_out;

    const int* src = ei;
    const int* dst = ei + N_EDGES;

    float* ws = (float*)d_ws;
    float* dinv    = ws + 0;                 // 100096
    float* pooled  = ws + 100096;            // 16384
    float* cntg    = ws + 116480;            // 128
    int*   cnt     = (int*)(ws + 116608);    // 100096
    int*   rowptr  = (int*)(ws + 216704);    // 100224
    int*   fill    = (int*)(ws + 316928);    // 100096
    int*   col     = (int*)(ws + 417024);    // 1600000
    float* h1      = ws + 2017024;           // 25600000
    float* agg     = ws + 27617024;          // 25600000

    const int B = 256;

    hipMemsetAsync(pooled, 0, (16384 + 128) * 4, stream);
    hipMemsetAsync(cnt, 0, (size_t)(417024 - 116608) * 4, stream);

    k_count<<<(N_EDGES + B - 1) / B, B, 0, stream>>>(dst, cnt);
    k_dinv<<<(N_NODES + B - 1) / B, B, 0, stream>>>(cnt, dinv);
    k_scan<<<1, 1024, 0, stream>>>(cnt, rowptr);
    k_fill<<<(N_EDGES + B - 1) / B, B, 0, stream>>>(src, dst, rowptr, fill, col);
    k_cnt<<<(N_NODES + B - 1) / B, B, 0, stream>>>(bat, cntg);

    // layer 1
    k_agg<IN_F><<<(N_NODES + 3) / 4, 256, 0, stream>>>(x, dinv, rowptr, cnt, col, agg);
    {
        dim3 grid((N_NODES + 127) / 128, HID / 128);
        k_gemm<IN_F, false><<<grid, 256, 0, stream>>>(agg, W1, b1, h1, nullptr, nullptr);
    }

    // layer 2
    k_agg<HID><<<(N_NODES + 3) / 4, 256, 0, stream>>>(h1, dinv, rowptr, cnt, col, agg);
    {
        dim3 grid((N_NODES + 127) / 128, HID / 128);
        k_gemm<HID, true><<<grid, 256, 0, stream>>>(agg, W2, b2, nullptr, bat, pooled);
    }

    k_final<<<(N_GRAPHS * OUT_F + B - 1) / B, B, 0, stream>>>(pooled, cntg, Wfc, bfc, out);
}

// Round 4
// 864.768 us; speedup vs baseline: 19.2054x; 1.8772x over previous
//
#include <hip/hip_runtime.h>

#define N_NODES 100000
#define N_EDGES 1600000
#define N_GRAPHS 64
#define IN_F 128
#define HID 256
#define OUT_F 10

#define SCAN_B 1024
#define SCAN_NB ((N_NODES + SCAN_B - 1) / SCAN_B)   // 98

// ---------------- CSR build ----------------
__global__ void k_count(const int* __restrict__ dst, int* __restrict__ cnt) {
    int e = blockIdx.x * blockDim.x + threadIdx.x;
    if (e < N_EDGES) atomicAdd(&cnt[dst[e]], 1);
}

__global__ void k_dinv(const int* __restrict__ cnt, float* __restrict__ dinv) {
    int i = blockIdx.x * blockDim.x + threadIdx.x;
    if (i < N_NODES) dinv[i] = rsqrtf((float)cnt[i] + 1.0f);  // +1 self loop
}

// multi-block exclusive scan: per-block scan + block sums
__global__ void k_scan1(const int* __restrict__ cnt, int* __restrict__ rowptr,
                        int* __restrict__ bsum) {
    __shared__ int sm[SCAN_B];
    int t = threadIdx.x, base = blockIdx.x * SCAN_B;
    int v = (base + t < N_NODES) ? cnt[base + t] : 0;
    int x = v;
    sm[t] = x;
    __syncthreads();
    for (int off = 1; off < SCAN_B; off <<= 1) {
        int add = (t >= off) ? sm[t - off] : 0;
        __syncthreads();
        x += add;
        sm[t] = x;
        __syncthreads();
    }
    if (base + t < N_NODES) rowptr[base + t] = x - v;   // exclusive within block
    if (t == SCAN_B - 1) bsum[blockIdx.x] = x;          // block total
}

__global__ void k_scan2(int* __restrict__ bsum) {
    __shared__ int sm[128];
    int t = threadIdx.x;
    int v = (t < SCAN_NB) ? bsum[t] : 0;
    int x = v;
    sm[t] = x;
    __syncthreads();
    for (int off = 1; off < 128; off <<= 1) {
        int add = (t >= off) ? sm[t - off] : 0;
        __syncthreads();
        x += add;
        sm[t] = x;
        __syncthreads();
    }
    if (t < SCAN_NB) bsum[t] = x - v;   // exclusive block offsets
}

__global__ void k_scan3(int* __restrict__ rowptr, const int* __restrict__ bsum) {
    int i = blockIdx.x * blockDim.x + threadIdx.x;
    if (i < N_NODES) rowptr[i] += bsum[i >> 10];
}

__global__ void k_fill(const int* __restrict__ src, const int* __restrict__ dst,
                       const int* __restrict__ rowptr, int* __restrict__ fill,
                       int* __restrict__ col) {
    int e = blockIdx.x * blockDim.x + threadIdx.x;
    if (e >= N_EDGES) return;
    int d = dst[e];
    int p = rowptr[d] + atomicAdd(&fill[d], 1);
    col[p] = src[e];
}

// ---------------- aggregation ----------------
template<int W>
__global__ void __launch_bounds__(256)
k_agg(const float* __restrict__ h, const float* __restrict__ dinv,
      const int* __restrict__ rowptr, const int* __restrict__ cnt,
      const int* __restrict__ col, float* __restrict__ out) {
    int wid = threadIdx.x >> 6, lane = threadIdx.x & 63;
    int i = blockIdx.x * 4 + wid;
    if (i >= N_NODES) return;
    float dd = dinv[i];
    int beg = rowptr[i], num = cnt[i];
    constexpr int V = W / 64;   // 2 or 4
    float acc[V];
    {
        const float* p = h + (size_t)i * W + lane * V;
        float s = dd * dd;
        if constexpr (V == 4) { float4 v = *(const float4*)p; acc[0]=s*v.x; acc[1]=s*v.y; acc[2]=s*v.z; acc[3]=s*v.w; }
        else                  { float2 v = *(const float2*)p; acc[0]=s*v.x; acc[1]=s*v.y; }
    }
    for (int k = 0; k < num; ++k) {
        int s = col[beg + k];
        float w = dd * dinv[s];
        const float* p = h + (size_t)s * W + lane * V;
        if constexpr (V == 4) { float4 v = *(const float4*)p; acc[0]+=w*v.x; acc[1]+=w*v.y; acc[2]+=w*v.z; acc[3]+=w*v.w; }
        else                  { float2 v = *(const float2*)p; acc[0]+=w*v.x; acc[1]+=w*v.y; }
    }
    float* o = out + (size_t)i * W + lane * V;
    if constexpr (V == 4) *(float4*)o = make_float4(acc[0], acc[1], acc[2], acc[3]);
    else                  *(float2*)o = make_float2(acc[0], acc[1]);
}

// ---------------- GEMM: C = relu(A @ W^T + bias), A:[M,K], W:[256,K] ----------------
// BM=128, BN=128, BK=32, 256 threads, 8x8 micro tile (split-64 cols), transposed LDS
template<int K, bool FUSE>
__global__ void __launch_bounds__(256)
k_gemm(const float* __restrict__ A, const float* __restrict__ Wm,
       const float* __restrict__ bias, float* __restrict__ C,
       const int* __restrict__ batch, float* __restrict__ pooled) {
    __shared__ float smem[2 * 32 * 132];
    float (*As)[132] = (float(*)[132])smem;            // [k][m]
    float (*Bs)[132] = (float(*)[132])(smem + 32*132); // [k][n]
    int row0 = blockIdx.x * 128;
    int col0 = blockIdx.y * 128;
    int t = threadIdx.x;
    int tm = t >> 4;   // 0..15 -> rows tm*8 .. tm*8+7
    int tn = t & 15;   // 0..15 -> cols tn*4..+3 and 64+tn*4..+3
    float acc[8][8] = {};
    for (int kc = 0; kc < K; kc += 32) {
        #pragma unroll
        for (int i = 0; i < 4; ++i) {
            int idx = i * 256 + t;            // 0..1023
            int r = idx >> 3;                 // 0..127
            int kq = idx & 7;                 // float4 within 32-k chunk
            int grow = row0 + r;
            float4 v = make_float4(0.f, 0.f, 0.f, 0.f);
            if (grow < N_NODES) v = *(const float4*)(A + (size_t)grow * K + kc + kq * 4);
            As[kq*4+0][r] = v.x; As[kq*4+1][r] = v.y; As[kq*4+2][r] = v.z; As[kq*4+3][r] = v.w;
        }
        #pragma unroll
        for (int i = 0; i < 4; ++i) {
            int idx = i * 256 + t;
            int r = idx >> 3;                 // 0..127 (n)
            int kq = idx & 7;
            float4 v = *(const float4*)(Wm + (size_t)(col0 + r) * K + kc + kq * 4);
            Bs[kq*4+0][r] = v.x; Bs[kq*4+1][r] = v.y; Bs[kq*4+2][r] = v.z; Bs[kq*4+3][r] = v.w;
        }
        __syncthreads();
        #pragma unroll 4
        for (int k = 0; k < 32; ++k) {
            float a[8], b[8];
            *(float4*)&a[0] = *(float4*)&As[k][tm * 8];
            *(float4*)&a[4] = *(float4*)&As[k][tm * 8 + 4];
            *(float4*)&b[0] = *(float4*)&Bs[k][tn * 4];        // banks 4tn..: 2-way, free
            *(float4*)&b[4] = *(float4*)&Bs[k][tn * 4 + 64];
            #pragma unroll
            for (int m = 0; m < 8; ++m)
                #pragma unroll
                for (int n = 0; n < 8; ++n)
                    acc[m][n] += a[m] * b[n];
        }
        __syncthreads();
    }
    // bias + relu into acc
    float bv[8];
    #pragma unroll
    for (int n = 0; n < 4; ++n) {
        bv[n]     = bias[col0 + tn * 4 + n];
        bv[4 + n] = bias[col0 + 64 + tn * 4 + n];
    }
    #pragma unroll
    for (int m = 0; m < 8; ++m)
        #pragma unroll
        for (int n = 0; n < 8; ++n)
            acc[m][n] = fmaxf(acc[m][n] + bv[n], 0.f);

    if (!FUSE) {
        #pragma unroll
        for (int m = 0; m < 8; ++m) {
            int grow = row0 + tm * 8 + m;
            if (grow >= N_NODES) continue;
            float* o = C + (size_t)grow * HID + col0;
            *(float4*)(o + tn * 4)      = make_float4(acc[m][0], acc[m][1], acc[m][2], acc[m][3]);
            *(float4*)(o + 64 + tn * 4) = make_float4(acc[m][4], acc[m][5], acc[m][6], acc[m][7]);
        }
    } else {
        // per-block segment reduction: batch is sorted -> few graphs per 128-row tile
        float* red = smem;   // [16][128], reuse (all LDS reads done at loop-end barrier)
        int rhi = row0 + 127; if (rhi >= N_NODES) rhi = N_NODES - 1;
        int glo = batch[row0], ghi = batch[rhi];
        int gm[8];
        #pragma unroll
        for (int m = 0; m < 8; ++m) {
            int grow = row0 + tm * 8 + m;
            gm[m] = (grow < N_NODES) ? batch[grow] : -1;
        }
        for (int g = glo; g <= ghi; ++g) {
            float p[8] = {};
            #pragma unroll
            for (int m = 0; m < 8; ++m)
                if (gm[m] == g) {
                    #pragma unroll
                    for (int n = 0; n < 8; ++n) p[n] += acc[m][n];
                }
            #pragma unroll
            for (int n = 0; n < 4; ++n) {
                red[tm * 128 + tn * 4 + n]      = p[n];
                red[tm * 128 + 64 + tn * 4 + n] = p[4 + n];
            }
            __syncthreads();
            if (t < 128) {
                float s = 0.f;
                #pragma unroll
                for (int r = 0; r < 16; ++r) s += red[r * 128 + t];
                if (s != 0.f) atomicAdd(&pooled[g * HID + col0 + t], s);
            }
            __syncthreads();
        }
    }
}

// ---------------- pooling counts (binary search over sorted batch) + final FC ----------------
__global__ void k_cntg_bs(const int* __restrict__ batch, float* __restrict__ cntg) {
    int g = threadIdx.x;
    if (g >= N_GRAPHS) return;
    int lo = 0, hi = N_NODES;
    while (lo < hi) { int mid = (lo + hi) >> 1; if (batch[mid] < g) lo = mid + 1; else hi = mid; }
    int a = lo;
    lo = 0; hi = N_NODES;
    while (lo < hi) { int mid = (lo + hi) >> 1; if (batch[mid] < g + 1) lo = mid + 1; else hi = mid; }
    cntg[g] = (float)(lo - a);
}

__global__ void k_final(const float* __restrict__ pooled, const float* __restrict__ cntg,
                        const float* __restrict__ Wfc, const float* __restrict__ bfc,
                        float* __restrict__ out) {
    int t = blockIdx.x * blockDim.x + threadIdx.x;
    if (t >= N_GRAPHS * OUT_F) return;
    int g = t / OUT_F, o = t % OUT_F;
    float inv = 1.0f / fmaxf(cntg[g], 1.0f);
    float s = 0.f;
    for (int k = 0; k < HID; ++k) s += pooled[g * HID + k] * Wfc[o * HID + k];
    out[t] = s * inv + bfc[o];
}

extern "C" void kernel_launch(void* const* d_in, const int* in_sizes, int n_in,
                              void* d_out, int out_size, void* d_ws, size_t ws_size,
                              hipStream_t stream) {
    const float* x    = (const float*)d_in[0];
    const int*   ei   = (const int*)d_in[1];
    const int*   bat  = (const int*)d_in[2];
    const float* W1   = (const float*)d_in[3];
    const float* b1   = (const float*)d_in[4];
    const float* W2   = (const float*)d_in[5];
    const float* b2   = (const float*)d_in[6];
    const float* Wfc  = (const float*)d_in[7];
    const float* bfc  = (const float*)d_in[8];
    float* out = (float*)d_out;

    const int* src = ei;
    const int* dst = ei + N_EDGES;

    float* ws = (float*)d_ws;
    float* dinv    = ws + 0;                 // 100096
    float* pooled  = ws + 100096;            // 16384
    float* cntg    = ws + 116480;            // 128
    int*   cnt     = (int*)(ws + 116608);    // 100096
    int*   rowptr  = (int*)(ws + 216704);    // 100224
    int*   fill    = (int*)(ws + 316928);    // 100096
    int*   bsum    = (int*)(ws + 416928);    // 128 (reused tail of fill pad)
    int*   col     = (int*)(ws + 417056);    // 1600000
    float* h1      = ws + 2017056;           // 25600000
    float* agg     = ws + 27617056;          // 25600000

    const int B = 256;

    hipMemsetAsync(pooled, 0, (16384 + 128) * 4, stream);
    hipMemsetAsync(cnt, 0, (size_t)(417056 - 116608) * 4, stream);

    k_count<<<(N_EDGES + B - 1) / B, B, 0, stream>>>(dst, cnt);
    k_dinv<<<(N_NODES + B - 1) / B, B, 0, stream>>>(cnt, dinv);
    k_scan1<<<SCAN_NB, SCAN_B, 0, stream>>>(cnt, rowptr, bsum);
    k_scan2<<<1, 128, 0, stream>>>(bsum);
    k_scan3<<<(N_NODES + B - 1) / B, B, 0, stream>>>(rowptr, bsum);
    k_fill<<<(N_EDGES + B - 1) / B, B, 0, stream>>>(src, dst, rowptr, fill, col);
    k_cntg_bs<<<1, 64, 0, stream>>>(bat, cntg);

    // layer 1
    k_agg<IN_F><<<(N_NODES + 3) / 4, 256, 0, stream>>>(x, dinv, rowptr, cnt, col, agg);
    {
        dim3 grid((N_NODES + 127) / 128, HID / 128);
        k_gemm<IN_F, false><<<grid, 256, 0, stream>>>(agg, W1, b1, h1, nullptr, nullptr);
    }

    // layer 2
    k_agg<HID><<<(N_NODES + 3) / 4, 256, 0, stream>>>(h1, dinv, rowptr, cnt, col, agg);
    {
        dim3 grid((N_NODES + 127) / 128, HID / 128);
        k_gemm<HID, true><<<grid, 256, 0, stream>>>(agg, W2, b2, nullptr, bat, pooled);
    }

    k_final<<<(N_GRAPHS * OUT_F + B - 1) / B, B, 0, stream>>>(pooled, cntg, Wfc, bfc, out);
}

// Round 5
// 800.362 us; speedup vs baseline: 20.7509x; 1.0805x over previous
//
#include <hip/hip_runtime.h>

#define N_NODES 100000
#define N_EDGES 1600000
#define N_GRAPHS 64
#define IN_F 128
#define HID 256
#define OUT_F 10

#define SCAN_B 1024
#define SCAN_NB ((N_NODES + SCAN_B - 1) / SCAN_B)   // 98

__device__ __forceinline__ unsigned short f2bf(float f) {
    unsigned int u = __float_as_uint(f);
    u += 0x7FFFu + ((u >> 16) & 1u);   // round-to-nearest-even
    return (unsigned short)(u >> 16);
}

// ---------------- CSR build ----------------
__global__ void k_count(const int* __restrict__ dst, int* __restrict__ cnt) {
    int e = blockIdx.x * blockDim.x + threadIdx.x;
    if (e < N_EDGES) atomicAdd(&cnt[dst[e]], 1);
}

__global__ void k_dinv(const int* __restrict__ cnt, float* __restrict__ dinv) {
    int i = blockIdx.x * blockDim.x + threadIdx.x;
    if (i < N_NODES) dinv[i] = rsqrtf((float)cnt[i] + 1.0f);  // +1 self loop
}

// prescaled bf16 copy of x: xb[i][c] = bf16(x[i][c] * dinv[i])
__global__ void k_xtobf(const float* __restrict__ x, const float* __restrict__ dinv,
                        unsigned short* __restrict__ xb) {
    int t = blockIdx.x * blockDim.x + threadIdx.x;   // N*16 threads, 8 elems each
    if (t >= N_NODES * (IN_F / 8)) return;
    int node = t / (IN_F / 8);
    float sc = dinv[node];
    const float* p = x + (size_t)t * 8;
    float4 a = *(const float4*)p;
    float4 b = *(const float4*)(p + 4);
    unsigned int o0 = f2bf(a.x * sc) | ((unsigned int)f2bf(a.y * sc) << 16);
    unsigned int o1 = f2bf(a.z * sc) | ((unsigned int)f2bf(a.w * sc) << 16);
    unsigned int o2 = f2bf(b.x * sc) | ((unsigned int)f2bf(b.y * sc) << 16);
    unsigned int o3 = f2bf(b.z * sc) | ((unsigned int)f2bf(b.w * sc) << 16);
    *(uint4*)(xb + (size_t)t * 8) = make_uint4(o0, o1, o2, o3);
}

// multi-block exclusive scan
__global__ void k_scan1(const int* __restrict__ cnt, int* __restrict__ rowptr,
                        int* __restrict__ bsum) {
    __shared__ int sm[SCAN_B];
    int t = threadIdx.x, base = blockIdx.x * SCAN_B;
    int v = (base + t < N_NODES) ? cnt[base + t] : 0;
    int x = v;
    sm[t] = x;
    __syncthreads();
    for (int off = 1; off < SCAN_B; off <<= 1) {
        int add = (t >= off) ? sm[t - off] : 0;
        __syncthreads();
        x += add;
        sm[t] = x;
        __syncthreads();
    }
    if (base + t < N_NODES) rowptr[base + t] = x - v;
    if (t == SCAN_B - 1) bsum[blockIdx.x] = x;
}

__global__ void k_scan2(int* __restrict__ bsum) {
    __shared__ int sm[128];
    int t = threadIdx.x;
    int v = (t < SCAN_NB) ? bsum[t] : 0;
    int x = v;
    sm[t] = x;
    __syncthreads();
    for (int off = 1; off < 128; off <<= 1) {
        int add = (t >= off) ? sm[t - off] : 0;
        __syncthreads();
        x += add;
        sm[t] = x;
        __syncthreads();
    }
    if (t < SCAN_NB) bsum[t] = x - v;
}

__global__ void k_scan3(int* __restrict__ rowptr, const int* __restrict__ bsum) {
    int i = blockIdx.x * blockDim.x + threadIdx.x;
    if (i < N_NODES) rowptr[i] += bsum[i >> 10];
}

__global__ void k_fill(const int* __restrict__ src, const int* __restrict__ dst,
                       const int* __restrict__ rowptr, int* __restrict__ fill,
                       int* __restrict__ col) {
    int e = blockIdx.x * blockDim.x + threadIdx.x;
    if (e >= N_EDGES) return;
    int d = dst[e];
    int p = rowptr[d] + atomicAdd(&fill[d], 1);
    col[p] = src[e];
}

// ---------------- aggregation (bf16 prescaled rows): out[i] = dinv[i]*(hb[i] + sum_j hb[j]) ----------------
template<int W>
__global__ void __launch_bounds__(256)
k_aggb(const unsigned short* __restrict__ hb, const float* __restrict__ dinv,
       const int* __restrict__ rowptr, const int* __restrict__ cnt,
       const int* __restrict__ col, float* __restrict__ out) {
    int wid = threadIdx.x >> 6, lane = threadIdx.x & 63;
    int i = blockIdx.x * 4 + wid;
    if (i >= N_NODES) return;
    float dd = dinv[i];
    int beg = rowptr[i], num = cnt[i];
    constexpr int V = W / 64;   // 2 or 4
    float acc[V];
    if constexpr (V == 2) {
        unsigned int u = *(const unsigned int*)(hb + (size_t)i * W + lane * 2);
        acc[0] = __uint_as_float((u & 0xffffu) << 16);
        acc[1] = __uint_as_float(u & 0xffff0000u);
    } else {
        uint2 u = *(const uint2*)(hb + (size_t)i * W + lane * 4);
        acc[0] = __uint_as_float((u.x & 0xffffu) << 16);
        acc[1] = __uint_as_float(u.x & 0xffff0000u);
        acc[2] = __uint_as_float((u.y & 0xffffu) << 16);
        acc[3] = __uint_as_float(u.y & 0xffff0000u);
    }
    for (int k = 0; k < num; ++k) {
        int s = col[beg + k];
        if constexpr (V == 2) {
            unsigned int u = *(const unsigned int*)(hb + (size_t)s * W + lane * 2);
            acc[0] += __uint_as_float((u & 0xffffu) << 16);
            acc[1] += __uint_as_float(u & 0xffff0000u);
        } else {
            uint2 u = *(const uint2*)(hb + (size_t)s * W + lane * 4);
            acc[0] += __uint_as_float((u.x & 0xffffu) << 16);
            acc[1] += __uint_as_float(u.x & 0xffff0000u);
            acc[2] += __uint_as_float((u.y & 0xffffu) << 16);
            acc[3] += __uint_as_float(u.y & 0xffff0000u);
        }
    }
    float* o = out + (size_t)i * W + lane * V;
    if constexpr (V == 2) *(float2*)o = make_float2(dd * acc[0], dd * acc[1]);
    else *(float4*)o = make_float4(dd * acc[0], dd * acc[1], dd * acc[2], dd * acc[3]);
}

// ---------------- GEMM: relu(A @ W^T + bias); A:[M,K] f32, W:[256,K] ----------------
// !FUSE: writes prescaled bf16 C (h1b[row][col] = bf16(relu(.)*dinv[row]))
// FUSE:  block-level segment reduce into pooled (batch sorted)
template<int K, bool FUSE>
__global__ void __launch_bounds__(256)
k_gemm(const float* __restrict__ A, const float* __restrict__ Wm,
       const float* __restrict__ bias, unsigned short* __restrict__ Cb,
       const float* __restrict__ dinv,
       const int* __restrict__ batch, float* __restrict__ pooled) {
    __shared__ float smem[2 * 32 * 132];
    float (*As)[132] = (float(*)[132])smem;            // [k][m]
    float (*Bs)[132] = (float(*)[132])(smem + 32*132); // [k][n]
    int row0 = blockIdx.x * 128;
    int col0 = blockIdx.y * 128;
    int t = threadIdx.x;
    int tm = t >> 4;
    int tn = t & 15;
    float acc[8][8] = {};
    for (int kc = 0; kc < K; kc += 32) {
        #pragma unroll
        for (int i = 0; i < 4; ++i) {
            int idx = i * 256 + t;
            int r = idx >> 3;
            int kq = idx & 7;
            int grow = row0 + r;
            float4 v = make_float4(0.f, 0.f, 0.f, 0.f);
            if (grow < N_NODES) v = *(const float4*)(A + (size_t)grow * K + kc + kq * 4);
            As[kq*4+0][r] = v.x; As[kq*4+1][r] = v.y; As[kq*4+2][r] = v.z; As[kq*4+3][r] = v.w;
        }
        #pragma unroll
        for (int i = 0; i < 4; ++i) {
            int idx = i * 256 + t;
            int r = idx >> 3;
            int kq = idx & 7;
            float4 v = *(const float4*)(Wm + (size_t)(col0 + r) * K + kc + kq * 4);
            Bs[kq*4+0][r] = v.x; Bs[kq*4+1][r] = v.y; Bs[kq*4+2][r] = v.z; Bs[kq*4+3][r] = v.w;
        }
        __syncthreads();
        #pragma unroll 4
        for (int k = 0; k < 32; ++k) {
            float a[8], b[8];
            *(float4*)&a[0] = *(float4*)&As[k][tm * 8];
            *(float4*)&a[4] = *(float4*)&As[k][tm * 8 + 4];
            *(float4*)&b[0] = *(float4*)&Bs[k][tn * 4];
            *(float4*)&b[4] = *(float4*)&Bs[k][tn * 4 + 64];
            #pragma unroll
            for (int m = 0; m < 8; ++m)
                #pragma unroll
                for (int n = 0; n < 8; ++n)
                    acc[m][n] += a[m] * b[n];
        }
        __syncthreads();
    }
    float bv[8];
    #pragma unroll
    for (int n = 0; n < 4; ++n) {
        bv[n]     = bias[col0 + tn * 4 + n];
        bv[4 + n] = bias[col0 + 64 + tn * 4 + n];
    }
    #pragma unroll
    for (int m = 0; m < 8; ++m)
        #pragma unroll
        for (int n = 0; n < 8; ++n)
            acc[m][n] = fmaxf(acc[m][n] + bv[n], 0.f);

    if (!FUSE) {
        #pragma unroll
        for (int m = 0; m < 8; ++m) {
            int grow = row0 + tm * 8 + m;
            if (grow >= N_NODES) continue;
            float sc = dinv[grow];
            unsigned short* o = Cb + (size_t)grow * HID + col0;
            unsigned int l0 = f2bf(acc[m][0]*sc) | ((unsigned int)f2bf(acc[m][1]*sc) << 16);
            unsigned int l1 = f2bf(acc[m][2]*sc) | ((unsigned int)f2bf(acc[m][3]*sc) << 16);
            unsigned int h0 = f2bf(acc[m][4]*sc) | ((unsigned int)f2bf(acc[m][5]*sc) << 16);
            unsigned int h1 = f2bf(acc[m][6]*sc) | ((unsigned int)f2bf(acc[m][7]*sc) << 16);
            *(uint2*)(o + tn * 4)      = make_uint2(l0, l1);
            *(uint2*)(o + 64 + tn * 4) = make_uint2(h0, h1);
        }
    } else {
        float* red = smem;   // [16][128] reuse
        int rhi = row0 + 127; if (rhi >= N_NODES) rhi = N_NODES - 1;
        int glo = batch[row0], ghi = batch[rhi];
        int gm[8];
        #pragma unroll
        for (int m = 0; m < 8; ++m) {
            int grow = row0 + tm * 8 + m;
            gm[m] = (grow < N_NODES) ? batch[grow] : -1;
        }
        for (int g = glo; g <= ghi; ++g) {
            float p[8] = {};
            #pragma unroll
            for (int m = 0; m < 8; ++m)
                if (gm[m] == g) {
                    #pragma unroll
                    for (int n = 0; n < 8; ++n) p[n] += acc[m][n];
                }
            #pragma unroll
            for (int n = 0; n < 4; ++n) {
                red[tm * 128 + tn * 4 + n]      = p[n];
                red[tm * 128 + 64 + tn * 4 + n] = p[4 + n];
            }
            __syncthreads();
            if (t < 128) {
                float s = 0.f;
                #pragma unroll
                for (int r = 0; r < 16; ++r) s += red[r * 128 + t];
                if (s != 0.f) atomicAdd(&pooled[g * HID + col0 + t], s);
            }
            __syncthreads();
        }
    }
}

// ---------------- pooling counts (binary search) + final FC ----------------
__global__ void k_cntg_bs(const int* __restrict__ batch, float* __restrict__ cntg) {
    int g = threadIdx.x;
    if (g >= N_GRAPHS) return;
    int lo = 0, hi = N_NODES;
    while (lo < hi) { int mid = (lo + hi) >> 1; if (batch[mid] < g) lo = mid + 1; else hi = mid; }
    int a = lo;
    lo = 0; hi = N_NODES;
    while (lo < hi) { int mid = (lo + hi) >> 1; if (batch[mid] < g + 1) lo = mid + 1; else hi = mid; }
    cntg[g] = (float)(lo - a);
}

__global__ void k_final(const float* __restrict__ pooled, const float* __restrict__ cntg,
                        const float* __restrict__ Wfc, const float* __restrict__ bfc,
                        float* __restrict__ out) {
    int t = blockIdx.x * blockDim.x + threadIdx.x;
    if (t >= N_GRAPHS * OUT_F) return;
    int g = t / OUT_F, o = t % OUT_F;
    float inv = 1.0f / fmaxf(cntg[g], 1.0f);
    float s = 0.f;
    for (int k = 0; k < HID; ++k) s += pooled[g * HID + k] * Wfc[o * HID + k];
    out[t] = s * inv + bfc[o];
}

extern "C" void kernel_launch(void* const* d_in, const int* in_sizes, int n_in,
                              void* d_out, int out_size, void* d_ws, size_t ws_size,
                              hipStream_t stream) {
    const float* x    = (const float*)d_in[0];
    const int*   ei   = (const int*)d_in[1];
    const int*   bat  = (const int*)d_in[2];
    const float* W1   = (const float*)d_in[3];
    const float* b1   = (const float*)d_in[4];
    const float* W2   = (const float*)d_in[5];
    const float* b2   = (const float*)d_in[6];
    const float* Wfc  = (const float*)d_in[7];
    const float* bfc  = (const float*)d_in[8];
    float* out = (float*)d_out;

    const int* src = ei;
    const int* dst = ei + N_EDGES;

    float* ws = (float*)d_ws;
    float* dinv    = ws + 0;                 // 100096
    float* pooled  = ws + 100096;            // 16384
    float* cntg    = ws + 116480;            // 128
    int*   cnt     = (int*)(ws + 116608);    // 100096
    int*   rowptr  = (int*)(ws + 216704);    // 100224
    int*   fill    = (int*)(ws + 316928);    // 100000
    int*   bsum    = (int*)(ws + 416928);    // 128
    int*   col     = (int*)(ws + 417056);    // 1600000
    unsigned short* xb  = (unsigned short*)(ws + 2017056);   // 100000*128 bf16 = 6.4M floats
    unsigned short* h1b = (unsigned short*)(ws + 8417056);   // 100000*256 bf16 = 12.8M floats
    float* agg     = ws + 21217056;          // 25600000 f32

    const int B = 256;

    hipMemsetAsync(pooled, 0, (16384 + 128) * 4, stream);
    hipMemsetAsync(cnt, 0, (size_t)(417056 - 116608) * 4, stream);

    k_count<<<(N_EDGES + B - 1) / B, B, 0, stream>>>(dst, cnt);
    k_dinv<<<(N_NODES + B - 1) / B, B, 0, stream>>>(cnt, dinv);
    k_xtobf<<<(N_NODES * (IN_F / 8) + B - 1) / B, B, 0, stream>>>(x, dinv, xb);
    k_scan1<<<SCAN_NB, SCAN_B, 0, stream>>>(cnt, rowptr, bsum);
    k_scan2<<<1, 128, 0, stream>>>(bsum);
    k_scan3<<<(N_NODES + B - 1) / B, B, 0, stream>>>(rowptr, bsum);
    k_fill<<<(N_EDGES + B - 1) / B, B, 0, stream>>>(src, dst, rowptr, fill, col);
    k_cntg_bs<<<1, 64, 0, stream>>>(bat, cntg);

    // layer 1: agg = A_hat @ x (bf16 gather), h1b = bf16(relu(agg@W1^T+b1)*dinv)
    k_aggb<IN_F><<<(N_NODES + 3) / 4, 256, 0, stream>>>(xb, dinv, rowptr, cnt, col, agg);
    {
        dim3 grid((N_NODES + 127) / 128, HID / 128);
        k_gemm<IN_F, false><<<grid, 256, 0, stream>>>(agg, W1, b1, h1b, dinv, nullptr, nullptr);
    }

    // layer 2: agg = A_hat @ h1 (bf16 gather), pooled += relu(agg@W2^T+b2)
    k_aggb<HID><<<(N_NODES + 3) / 4, 256, 0, stream>>>(h1b, dinv, rowptr, cnt, col, agg);
    {
        dim3 grid((N_NODES + 127) / 128, HID / 128);
        k_gemm<HID, true><<<grid, 256, 0, stream>>>(agg, W2, b2, nullptr, nullptr, bat, pooled);
    }

    k_final<<<(N_GRAPHS * OUT_F + B - 1) / B, B, 0, stream>>>(pooled, cntg, Wfc, bfc, out);
}

// Round 6
// 615.974 us; speedup vs baseline: 26.9625x; 1.2993x over previous
//
#include <hip/hip_runtime.h>

#define N_NODES 100000
#define N_EDGES 1600000
#define N_GRAPHS 64
#define IN_F 128
#define HID 256
#define OUT_F 10

#define SCAN_B 1024
#define SCAN_NB ((N_NODES + SCAN_B - 1) / SCAN_B)   // 98

typedef __attribute__((ext_vector_type(8))) short short8v;
typedef __attribute__((ext_vector_type(4))) float f32x4;

__device__ __forceinline__ unsigned short f2bf(float f) {
    unsigned int u = __float_as_uint(f);
    u += 0x7FFFu + ((u >> 16) & 1u);   // round-to-nearest-even
    return (unsigned short)(u >> 16);
}

// ---------------- CSR build ----------------
__global__ void k_count(const int* __restrict__ dst, int* __restrict__ cnt) {
    int e = blockIdx.x * blockDim.x + threadIdx.x;
    if (e < N_EDGES) atomicAdd(&cnt[dst[e]], 1);
}

__global__ void k_dinv(const int* __restrict__ cnt, float* __restrict__ dinv) {
    int i = blockIdx.x * blockDim.x + threadIdx.x;
    if (i < N_NODES) dinv[i] = rsqrtf((float)cnt[i] + 1.0f);  // +1 self loop
}

// f32 -> bf16 bulk convert (8 elems/thread)
__global__ void k_tobf(const float* __restrict__ w, unsigned short* __restrict__ wb, int n8) {
    int t = blockIdx.x * blockDim.x + threadIdx.x;
    if (t >= n8) return;
    const float* p = w + (size_t)t * 8;
    float4 a = *(const float4*)p;
    float4 b = *(const float4*)(p + 4);
    unsigned int o0 = f2bf(a.x) | ((unsigned int)f2bf(a.y) << 16);
    unsigned int o1 = f2bf(a.z) | ((unsigned int)f2bf(a.w) << 16);
    unsigned int o2 = f2bf(b.x) | ((unsigned int)f2bf(b.y) << 16);
    unsigned int o3 = f2bf(b.z) | ((unsigned int)f2bf(b.w) << 16);
    *(uint4*)(wb + (size_t)t * 8) = make_uint4(o0, o1, o2, o3);
}

// prescaled bf16 copy of x: xb[i][c] = bf16(x[i][c] * dinv[i])
__global__ void k_xtobf(const float* __restrict__ x, const float* __restrict__ dinv,
                        unsigned short* __restrict__ xb) {
    int t = blockIdx.x * blockDim.x + threadIdx.x;
    if (t >= N_NODES * (IN_F / 8)) return;
    int node = t / (IN_F / 8);
    float sc = dinv[node];
    const float* p = x + (size_t)t * 8;
    float4 a = *(const float4*)p;
    float4 b = *(const float4*)(p + 4);
    unsigned int o0 = f2bf(a.x * sc) | ((unsigned int)f2bf(a.y * sc) << 16);
    unsigned int o1 = f2bf(a.z * sc) | ((unsigned int)f2bf(a.w * sc) << 16);
    unsigned int o2 = f2bf(b.x * sc) | ((unsigned int)f2bf(b.y * sc) << 16);
    unsigned int o3 = f2bf(b.z * sc) | ((unsigned int)f2bf(b.w * sc) << 16);
    *(uint4*)(xb + (size_t)t * 8) = make_uint4(o0, o1, o2, o3);
}

// multi-block exclusive scan
__global__ void k_scan1(const int* __restrict__ cnt, int* __restrict__ rowptr,
                        int* __restrict__ bsum) {
    __shared__ int sm[SCAN_B];
    int t = threadIdx.x, base = blockIdx.x * SCAN_B;
    int v = (base + t < N_NODES) ? cnt[base + t] : 0;
    int x = v;
    sm[t] = x;
    __syncthreads();
    for (int off = 1; off < SCAN_B; off <<= 1) {
        int add = (t >= off) ? sm[t - off] : 0;
        __syncthreads();
        x += add;
        sm[t] = x;
        __syncthreads();
    }
    if (base + t < N_NODES) rowptr[base + t] = x - v;
    if (t == SCAN_B - 1) bsum[blockIdx.x] = x;
}

__global__ void k_scan2(int* __restrict__ bsum) {
    __shared__ int sm[128];
    int t = threadIdx.x;
    int v = (t < SCAN_NB) ? bsum[t] : 0;
    int x = v;
    sm[t] = x;
    __syncthreads();
    for (int off = 1; off < 128; off <<= 1) {
        int add = (t >= off) ? sm[t - off] : 0;
        __syncthreads();
        x += add;
        sm[t] = x;
        __syncthreads();
    }
    if (t < SCAN_NB) bsum[t] = x - v;
}

__global__ void k_scan3(int* __restrict__ rowptr, const int* __restrict__ bsum) {
    int i = blockIdx.x * blockDim.x + threadIdx.x;
    if (i < N_NODES) rowptr[i] += bsum[i >> 10];
}

__global__ void k_fill(const int* __restrict__ src, const int* __restrict__ dst,
                       const int* __restrict__ rowptr, int* __restrict__ fill,
                       int* __restrict__ col) {
    int e = blockIdx.x * blockDim.x + threadIdx.x;
    if (e >= N_EDGES) return;
    int d = dst[e];
    int p = rowptr[d] + atomicAdd(&fill[d], 1);
    col[p] = src[e];
}

// ---------------- aggregation (bf16 prescaled rows -> bf16 out) ----------------
// out[i] = bf16( dinv[i] * (hb[i] + sum_j hb[j]) )
template<int W>
__global__ void __launch_bounds__(256)
k_aggb(const unsigned short* __restrict__ hb, const float* __restrict__ dinv,
       const int* __restrict__ rowptr, const int* __restrict__ cnt,
       const int* __restrict__ col, unsigned short* __restrict__ out) {
    int wid = threadIdx.x >> 6, lane = threadIdx.x & 63;
    int i = blockIdx.x * 4 + wid;
    if (i >= N_NODES) return;
    float dd = dinv[i];
    int beg = rowptr[i], num = cnt[i];
    constexpr int V = W / 64;   // 2 or 4
    float acc[V];
    if constexpr (V == 2) {
        unsigned int u = *(const unsigned int*)(hb + (size_t)i * W + lane * 2);
        acc[0] = __uint_as_float((u & 0xffffu) << 16);
        acc[1] = __uint_as_float(u & 0xffff0000u);
    } else {
        uint2 u = *(const uint2*)(hb + (size_t)i * W + lane * 4);
        acc[0] = __uint_as_float((u.x & 0xffffu) << 16);
        acc[1] = __uint_as_float(u.x & 0xffff0000u);
        acc[2] = __uint_as_float((u.y & 0xffffu) << 16);
        acc[3] = __uint_as_float(u.y & 0xffff0000u);
    }
    for (int k = 0; k < num; ++k) {
        int s = col[beg + k];
        if constexpr (V == 2) {
            unsigned int u = *(const unsigned int*)(hb + (size_t)s * W + lane * 2);
            acc[0] += __uint_as_float((u & 0xffffu) << 16);
            acc[1] += __uint_as_float(u & 0xffff0000u);
        } else {
            uint2 u = *(const uint2*)(hb + (size_t)s * W + lane * 4);
            acc[0] += __uint_as_float((u.x & 0xffffu) << 16);
            acc[1] += __uint_as_float(u.x & 0xffff0000u);
            acc[2] += __uint_as_float((u.y & 0xffffu) << 16);
            acc[3] += __uint_as_float(u.y & 0xffff0000u);
        }
    }
    if constexpr (V == 2) {
        unsigned int o = f2bf(dd * acc[0]) | ((unsigned int)f2bf(dd * acc[1]) << 16);
        *(unsigned int*)(out + (size_t)i * W + lane * 2) = o;
    } else {
        unsigned int o0 = f2bf(dd * acc[0]) | ((unsigned int)f2bf(dd * acc[1]) << 16);
        unsigned int o1 = f2bf(dd * acc[2]) | ((unsigned int)f2bf(dd * acc[3]) << 16);
        *(uint2*)(out + (size_t)i * W + lane * 4) = make_uint2(o0, o1);
    }
}

// ---------------- MFMA GEMM: relu(A @ W^T + bias); A:[M,K] bf16, W:[256,K] bf16 ----------------
// BM=128, BN=128, BK=64, 256 threads = 4 waves (2x2), each wave 64x64 via 4x4 16x16x32 frags.
// !FUSE: Cb[row][col] = bf16(relu(.) * dinv[row]);  FUSE: segment-reduce into pooled.
template<int K, bool FUSE>
__global__ void __launch_bounds__(256)
k_mgemm(const unsigned short* __restrict__ A, const unsigned short* __restrict__ Wb,
        const float* __restrict__ bias, unsigned short* __restrict__ Cb,
        const float* __restrict__ dinv, const int* __restrict__ batch,
        float* __restrict__ pooled) {
    constexpr int LDT = 72;   // padded row stride (shorts); 144B -> uniform bank spread
    __shared__ unsigned short Asl[128 * LDT];
    __shared__ unsigned short Bsl[128 * LDT];
    __shared__ float red[128];
    int row0 = blockIdx.x * 128;
    int col0 = blockIdx.y * 128;
    int t = threadIdx.x;
    int wid = t >> 6, lane = t & 63;
    int fr = lane & 15, fq = lane >> 4;
    int wr = wid >> 1, wc = wid & 1;

    f32x4 acc[4][4] = {};

    for (int kc = 0; kc < K; kc += 64) {
        #pragma unroll
        for (int p = 0; p < 4; ++p) {
            int idx = p * 256 + t;            // 0..1023
            int r = idx >> 3;                 // 0..127
            int c8 = (idx & 7) * 8;           // bf16 col
            uint4 v = make_uint4(0u, 0u, 0u, 0u);
            int grow = row0 + r;
            if (grow < N_NODES) v = *(const uint4*)(A + (size_t)grow * K + kc + c8);
            *(uint4*)(Asl + r * LDT + c8) = v;
            uint4 w = *(const uint4*)(Wb + (size_t)(col0 + r) * K + kc + c8);
            *(uint4*)(Bsl + r * LDT + c8) = w;
        }
        __syncthreads();
        #pragma unroll
        for (int k0 = 0; k0 < 64; k0 += 32) {
            short8v af[4], bf[4];
            #pragma unroll
            for (int m = 0; m < 4; ++m)
                af[m] = *(const short8v*)(Asl + (wr * 64 + m * 16 + fr) * LDT + k0 + fq * 8);
            #pragma unroll
            for (int n = 0; n < 4; ++n)
                bf[n] = *(const short8v*)(Bsl + (wc * 64 + n * 16 + fr) * LDT + k0 + fq * 8);
            #pragma unroll
            for (int m = 0; m < 4; ++m)
                #pragma unroll
                for (int n = 0; n < 4; ++n)
                    acc[m][n] = __builtin_amdgcn_mfma_f32_16x16x32_bf16(af[m], bf[n], acc[m][n], 0, 0, 0);
        }
        __syncthreads();
    }

    float bv[4];
    #pragma unroll
    for (int n = 0; n < 4; ++n) bv[n] = bias[col0 + wc * 64 + n * 16 + fr];

    if (!FUSE) {
        #pragma unroll
        for (int m = 0; m < 4; ++m) {
            #pragma unroll
            for (int j = 0; j < 4; ++j) {
                int row = row0 + wr * 64 + m * 16 + fq * 4 + j;
                if (row >= N_NODES) continue;
                float sc = dinv[row];
                unsigned short* o = Cb + (size_t)row * HID + col0 + wc * 64;
                #pragma unroll
                for (int n = 0; n < 4; ++n) {
                    float v = fmaxf(acc[m][n][j] + bv[n], 0.f) * sc;
                    o[n * 16 + fr] = f2bf(v);
                }
            }
        }
    } else {
        int gm[4][4];
        #pragma unroll
        for (int m = 0; m < 4; ++m)
            #pragma unroll
            for (int j = 0; j < 4; ++j) {
                int row = row0 + wr * 64 + m * 16 + fq * 4 + j;
                gm[m][j] = (row < N_NODES) ? batch[row] : -1;
                #pragma unroll
                for (int n = 0; n < 4; ++n)
                    acc[m][n][j] = fmaxf(acc[m][n][j] + bv[n], 0.f);
            }
        int rhi = row0 + 127; if (rhi >= N_NODES) rhi = N_NODES - 1;
        int glo = batch[row0], ghi = batch[rhi];
        for (int g = glo; g <= ghi; ++g) {
            if (t < 128) red[t] = 0.f;
            __syncthreads();
            #pragma unroll
            for (int n = 0; n < 4; ++n) {
                float s = 0.f;
                #pragma unroll
                for (int m = 0; m < 4; ++m)
                    #pragma unroll
                    for (int j = 0; j < 4; ++j)
                        if (gm[m][j] == g) s += acc[m][n][j];
                if (s != 0.f) atomicAdd(&red[wc * 64 + n * 16 + fr], s);
            }
            __syncthreads();
            if (t < 128 && red[t] != 0.f)
                atomicAdd(&pooled[g * HID + col0 + t], red[t]);
            __syncthreads();
        }
    }
}

// ---------------- pooling counts (binary search) + final FC ----------------
__global__ void k_cntg_bs(const int* __restrict__ batch, float* __restrict__ cntg) {
    int g = threadIdx.x;
    if (g >= N_GRAPHS) return;
    int lo = 0, hi = N_NODES;
    while (lo < hi) { int mid = (lo + hi) >> 1; if (batch[mid] < g) lo = mid + 1; else hi = mid; }
    int a = lo;
    lo = 0; hi = N_NODES;
    while (lo < hi) { int mid = (lo + hi) >> 1; if (batch[mid] < g + 1) lo = mid + 1; else hi = mid; }
    cntg[g] = (float)(lo - a);
}

__global__ void k_final(const float* __restrict__ pooled, const float* __restrict__ cntg,
                        const float* __restrict__ Wfc, const float* __restrict__ bfc,
                        float* __restrict__ out) {
    int t = blockIdx.x * blockDim.x + threadIdx.x;
    if (t >= N_GRAPHS * OUT_F) return;
    int g = t / OUT_F, o = t % OUT_F;
    float inv = 1.0f / fmaxf(cntg[g], 1.0f);
    float s = 0.f;
    for (int k = 0; k < HID; ++k) s += pooled[g * HID + k] * Wfc[o * HID + k];
    out[t] = s * inv + bfc[o];
}

extern "C" void kernel_launch(void* const* d_in, const int* in_sizes, int n_in,
                              void* d_out, int out_size, void* d_ws, size_t ws_size,
                              hipStream_t stream) {
    const float* x    = (const float*)d_in[0];
    const int*   ei   = (const int*)d_in[1];
    const int*   bat  = (const int*)d_in[2];
    const float* W1   = (const float*)d_in[3];
    const float* b1   = (const float*)d_in[4];
    const float* W2   = (const float*)d_in[5];
    const float* b2   = (const float*)d_in[6];
    const float* Wfc  = (const float*)d_in[7];
    const float* bfc  = (const float*)d_in[8];
    float* out = (float*)d_out;

    const int* src = ei;
    const int* dst = ei + N_EDGES;

    float* ws = (float*)d_ws;
    float* dinv    = ws + 0;                 // 100096
    float* pooled  = ws + 100096;            // 16384
    float* cntg    = ws + 116480;            // 128
    int*   cnt     = (int*)(ws + 116608);    // 100096
    int*   rowptr  = (int*)(ws + 216704);    // 100224
    int*   fill    = (int*)(ws + 316928);    // 100000
    int*   bsum    = (int*)(ws + 416928);    // 128
    int*   col     = (int*)(ws + 417056);    // 1600000
    unsigned short* W1b = (unsigned short*)(ws + 2017056);   // 32768 bf16
    unsigned short* W2b = (unsigned short*)(ws + 2033440);   // 65536 bf16
    unsigned short* xb  = (unsigned short*)(ws + 2066208);   // 100000*128 bf16
    unsigned short* h1b = (unsigned short*)(ws + 8466208);   // 100000*256 bf16
    unsigned short* aggb = (unsigned short*)(ws + 21266208); // up to 100000*256 bf16

    const int B = 256;

    hipMemsetAsync(pooled, 0, (16384 + 128) * 4, stream);
    hipMemsetAsync(cnt, 0, (size_t)(417056 - 116608) * 4, stream);

    k_count<<<(N_EDGES + B - 1) / B, B, 0, stream>>>(dst, cnt);
    k_dinv<<<(N_NODES + B - 1) / B, B, 0, stream>>>(cnt, dinv);
    k_tobf<<<(HID * IN_F / 8 + B - 1) / B, B, 0, stream>>>(W1, W1b, HID * IN_F / 8);
    k_tobf<<<(HID * HID / 8 + B - 1) / B, B, 0, stream>>>(W2, W2b, HID * HID / 8);
    k_xtobf<<<(N_NODES * (IN_F / 8) + B - 1) / B, B, 0, stream>>>(x, dinv, xb);
    k_scan1<<<SCAN_NB, SCAN_B, 0, stream>>>(cnt, rowptr, bsum);
    k_scan2<<<1, 128, 0, stream>>>(bsum);
    k_scan3<<<(N_NODES + B - 1) / B, B, 0, stream>>>(rowptr, bsum);
    k_fill<<<(N_EDGES + B - 1) / B, B, 0, stream>>>(src, dst, rowptr, fill, col);
    k_cntg_bs<<<1, 64, 0, stream>>>(bat, cntg);

    // layer 1: aggb = bf16(A_hat @ x), h1b = bf16(relu(aggb@W1^T+b1)*dinv)
    k_aggb<IN_F><<<(N_NODES + 3) / 4, 256, 0, stream>>>(xb, dinv, rowptr, cnt, col, aggb);
    {
        dim3 grid((N_NODES + 127) / 128, HID / 128);
        k_mgemm<IN_F, false><<<grid, 256, 0, stream>>>(aggb, W1b, b1, h1b, dinv, nullptr, nullptr);
    }

    // layer 2: aggb = bf16(A_hat @ h1), pooled += relu(aggb@W2^T+b2) segment-reduced
    k_aggb<HID><<<(N_NODES + 3) / 4, 256, 0, stream>>>(h1b, dinv, rowptr, cnt, col, aggb);
    {
        dim3 grid((N_NODES + 127) / 128, HID / 128);
        k_mgemm<HID, true><<<grid, 256, 0, stream>>>(aggb, W2b, b2, nullptr, nullptr, bat, pooled);
    }

    k_final<<<(N_GRAPHS * OUT_F + B - 1) / B, B, 0, stream>>>(pooled, cntg, Wfc, bfc, out);
}